// Round 1
// baseline (153.210 us; speedup 1.0000x reference)
//
#include <hip/hip_runtime.h>
#include <hip/hip_bf16.h>

// BERT_CRF fused: emissions (MFMA) + CRF NLL in ONE kernel.
// B=64, T=512, H=768, L=9. Output: single f32 scalar.
//
// Grid 512 x 320. Waves 0..3 of each block compute 4 x 16-row emission
// tiles (rows blockIdx*64 .. +63, all inside batch b = blockIdx/8) exactly
// as the previous emis_kernel. Then: __threadfence (all threads, release),
// __syncthreads, thread 0 atomicAdd(&bcnt[b],1). The 8th finisher block
// for a batch becomes that batch's CRF consumer and runs the R4-proven
// 320-thread fwd body (NCH=32, CS=16, pair-combine, serial combine) on
// the freshly written eexp. threadFenceReduction pattern: no spin-waits,
// correct under any dispatch order / XCD placement.
// CRF LDS overlays the dead W-fragment region (24.6 KB total).
// bcnt[64] + cnt2 zeroed by a 260-B hipMemsetAsync node (workspace is
// poisoned between iterations, so counters must be re-initialized).

#define Bn 64
#define Tn 512
#define Hn 768
#define Ln 9
#define EMS 12     // padded emission row stride (floats)
#define CS 16      // time steps per chunk (fwd)
#define NCH 32     // chunks covering t=1..511
#define KSTEPS 24  // 768 / 32

typedef short bf16x8 __attribute__((ext_vector_type(8)));   // 8 bf16 (4 VGPRs)
typedef float f32x4  __attribute__((ext_vector_type(4)));   // 4 fp32 acc

__device__ __forceinline__ short f2bf(float f) {
    return (short)__builtin_bit_cast(unsigned short, __float2bfloat16(f));
}

__global__ __launch_bounds__(320) void fused_kernel(
    const float* __restrict__ wv, const float* __restrict__ Wm,
    const float* __restrict__ bias, const int* __restrict__ mask,
    const int* __restrict__ label, const float* __restrict__ trans,
    const float* __restrict__ startT, const float* __restrict__ endT,
    float* __restrict__ eexp, float* __restrict__ partial,
    int* __restrict__ bcnt, int* __restrict__ cnt2,
    float* __restrict__ out)
{
    // 24576 B: wlds (emission) overlaid later by CRF arrays.
    __shared__ __align__(16) char smraw[24576];
    __shared__ float sp[5];
    __shared__ int   si[5];
    __shared__ int   sFlag;

    const int tid  = threadIdx.x;
    const int lane = tid & 63;
    const int wid  = tid >> 6;

    // ---------------- emission phase ----------------
    // Stage W (L=9 x H=768 fp32) as bf16 B-fragments in MFMA lane order.
    bf16x8* wlds = reinterpret_cast<bf16x8*>(smraw);
    for (int idx = tid; idx < KSTEPS * 64; idx += 320) {
        const int kk = idx >> 6, ln = idx & 63;
        const int n = ln & 15, kb2 = ln >> 4;
        bf16x8 v;
        if (n < Ln) {
            const float* src = Wm + n * Hn + kk * 32 + kb2 * 8;
#pragma unroll
            for (int j = 0; j < 8; ++j) v[j] = f2bf(src[j]);
        } else {
#pragma unroll
            for (int j = 0; j < 8; ++j) v[j] = 0;
        }
        wlds[idx] = v;
    }
    __syncthreads();

    if (wid < 4) {
        const int tile = (blockIdx.x << 2) + wid;          // 2048 tiles
        const int m    = lane & 15;                        // A row within tile
        const int kb   = lane >> 4;                        // k-subblock (8 elems)
        const float* abase = wv + (size_t)(tile * 16 + m) * Hn + kb * 8;

        f32x4 acc = {0.f, 0.f, 0.f, 0.f};
#pragma unroll 4
        for (int kk = 0; kk < KSTEPS; ++kk) {
            float4 x0 = *reinterpret_cast<const float4*>(abase + kk * 32);
            float4 x1 = *reinterpret_cast<const float4*>(abase + kk * 32 + 4);
            bf16x8 a;
            a[0] = f2bf(x0.x); a[1] = f2bf(x0.y); a[2] = f2bf(x0.z); a[3] = f2bf(x0.w);
            a[4] = f2bf(x1.x); a[5] = f2bf(x1.y); a[6] = f2bf(x1.z); a[7] = f2bf(x1.w);
            bf16x8 bfr = wlds[kk * 64 + lane];
            acc = __builtin_amdgcn_mfma_f32_16x16x32_bf16(a, bfr, acc, 0, 0, 0);
        }

        // Epilogue: C/D layout col = lane&15, row = (lane>>4)*4 + reg.
        const int l = lane & 15;
        if (l < Ln) {
            const float bl = bias[l];
#pragma unroll
            for (int r = 0; r < 4; ++r) {
                const int row = tile * 16 + (lane >> 4) * 4 + r;
                eexp[(size_t)row * EMS + l] = __expf(acc[r] + bl);
            }
        }
    }

    // ---------------- publish + consumer election ----------------
    __threadfence();            // release: every thread's eexp stores device-visible
    __syncthreads();
    const int b = blockIdx.x >> 3;   // 8 producer blocks per batch
    if (tid == 0) sFlag = (atomicAdd(&bcnt[b], 1) == 7);
    __syncthreads();
    if (!sFlag) return;         // uniform per block
    __threadfence();            // acquire: other producers' eexp visible

    // ---------------- CRF forward (R4-proven 320-thread body) ----------------
    float (*sM)[Ln][Ln]  = reinterpret_cast<float(*)[Ln][Ln]>(smraw);          // [32][9][9]
    float (*sLg)[Ln]     = reinterpret_cast<float(*)[Ln]>(smraw + 10368);      // [32][9]
    float (*sM2)[Ln][Ln] = reinterpret_cast<float(*)[Ln][Ln]>(smraw + 11520);  // [16][9][9]
    float (*sLg2)[Ln]    = reinterpret_cast<float(*)[Ln]>(smraw + 16704);      // [16][9]
    float* eTs           = reinterpret_cast<float*>(smraw + 17280);            // [81]

    if (tid < 81) eTs[tid] = __expf(trans[tid]);

    // ---- Phase 1: numerator partials ----
    float part = 0.f; int msum = 0;
    for (int t = tid; t < Tn; t += 320) {
        int tag = label[b * Tn + t];
        int mk  = mask[b * Tn + t];
        msum += mk;
        if (t == 0) {
            part += startT[tag] + __logf(eexp[(size_t)(b * Tn) * EMS + tag]);
        } else if (mk) {
            int prev = label[b * Tn + t - 1];
            part += trans[prev * Ln + tag] + __logf(eexp[(size_t)(b * Tn + t) * EMS + tag]);
        }
    }
#pragma unroll
    for (int off = 32; off > 0; off >>= 1) {
        part += __shfl_xor(part, off);
        msum += __shfl_xor(msum, off);
    }
    if (lane == 0) { sp[wid] = part; si[wid] = msum; }

    __syncthreads();   // eTs + numerator partials ready

    // ---- Phase 2: chunk products (threads 0..287) ----
    if (tid < NCH * Ln) {
        float Tr[81];
#pragma unroll
        for (int i = 0; i < 81; ++i) Tr[i] = eTs[i];
        const int r = tid % Ln;
        const int c = tid / Ln;

        float v[9];
#pragma unroll
        for (int k = 0; k < 9; ++k) v[k] = (k == r) ? 1.f : 0.f;
        float lg = 0.f;

        const int t0 = 1 + c * CS;
        const int t1 = min(Tn, t0 + CS);
        const float* eb = eexp + (size_t)(b * Tn) * EMS;
        const int* mrow = mask + b * Tn;

        float4 e0 = *reinterpret_cast<const float4*>(eb + t0 * EMS);
        float4 e1 = *reinterpret_cast<const float4*>(eb + t0 * EMS + 4);
        float  e8 = eb[t0 * EMS + 8];
        int    mk = mrow[t0];

        for (int t = t0; t < t1; ++t) {
            float4 p0 = make_float4(0.f, 0.f, 0.f, 0.f), p1 = p0;
            float  p8 = 0.f; int pm = 0;
            if (t + 1 < t1) {
                p0 = *reinterpret_cast<const float4*>(eb + (t + 1) * EMS);
                p1 = *reinterpret_cast<const float4*>(eb + (t + 1) * EMS + 4);
                p8 = eb[(t + 1) * EMS + 8];
                pm = mrow[t + 1];
            }
            if (mk) {
                float e[9] = {e0.x, e0.y, e0.z, e0.w, e1.x, e1.y, e1.z, e1.w, e8};
                float nv[9];
#pragma unroll
                for (int jj = 0; jj < 9; ++jj) {
                    float acc = v[0] * Tr[jj];
#pragma unroll
                    for (int k = 1; k < 9; ++k) acc += v[k] * Tr[k * 9 + jj];
                    nv[jj] = acc * e[jj];
                }
                float mx = nv[0];
#pragma unroll
                for (int jj = 1; jj < 9; ++jj) mx = fmaxf(mx, nv[jj]);
                float inv = 1.f / mx;
#pragma unroll
                for (int jj = 0; jj < 9; ++jj) v[jj] = nv[jj] * inv;
                lg += __logf(mx);
            }
            e0 = p0; e1 = p1; e8 = p8; mk = pm;
        }
#pragma unroll
        for (int jj = 0; jj < 9; ++jj) sM[c][r][jj] = v[jj];
        sLg[c][r] = lg;
    }
    __syncthreads();

    // ---- Phase 2.5: pair-combine 32 -> 16 (threads 0..143) ----
    if (tid < (NCH / 2) * Ln) {
        const int r = tid % Ln;
        const int p = tid / Ln;            // pair p: combines chunks 2p, 2p+1
        float mB = sLg[2 * p + 1][0];
#pragma unroll
        for (int k = 1; k < 9; ++k) mB = fmaxf(mB, sLg[2 * p + 1][k]);
        float tA[9];
#pragma unroll
        for (int k = 0; k < 9; ++k) tA[k] = sM[2 * p][r][k] * __expf(sLg[2 * p + 1][k] - mB);
        float v[9];
#pragma unroll
        for (int jj = 0; jj < 9; ++jj) {
            float acc = tA[0] * sM[2 * p + 1][0][jj];
#pragma unroll
            for (int k = 1; k < 9; ++k) acc += tA[k] * sM[2 * p + 1][k][jj];
            v[jj] = acc;
        }
        float mx = v[0];
#pragma unroll
        for (int jj = 1; jj < 9; ++jj) mx = fmaxf(mx, v[jj]);
        float inv = 1.f / mx;
#pragma unroll
        for (int jj = 0; jj < 9; ++jj) sM2[p][r][jj] = v[jj] * inv;
        sLg2[p][r] = sLg[2 * p][r] + mB + __logf(mx);
    }
    __syncthreads();

    // ---- Phase 3: serial combine of 16 from LDS + denominator (lanes 0..15) ----
    if (tid < 16) {
        const int lj = tid;
        const float NEG = -1e30f;
        float la = (lj < Ln) ? (startT[lj] + __logf(eexp[(size_t)(b * Tn) * EMS + lj])) : NEG;
        for (int c = 0; c < NCH / 2; ++c) {
            float mc[9];
#pragma unroll
            for (int rr = 0; rr < 9; ++rr) mc[rr] = (lj < Ln) ? sM2[c][rr][lj] : 0.f;
            float x = (lj < Ln) ? (la + sLg2[c][lj]) : NEG;
            float mm = x;
#pragma unroll
            for (int off = 1; off < 16; off <<= 1) mm = fmaxf(mm, __shfl_xor(mm, off, 16));
            float w = __expf(x - mm);                 // lj>=9 -> 0
            float sacc = 0.f;
#pragma unroll
            for (int rr = 0; rr < 9; ++rr) sacc += __shfl(w, rr, 16) * mc[rr];
            la = (lj < Ln) ? (mm + __logf(sacc)) : NEG;
        }
        float x = (lj < Ln) ? (la + endT[lj]) : NEG;
        float mm = x;
#pragma unroll
        for (int off = 1; off < 16; off <<= 1) mm = fmaxf(mm, __shfl_xor(mm, off, 16));
        float se = __expf(x - mm);
#pragma unroll
        for (int off = 1; off < 16; off <<= 1) se += __shfl_xor(se, off, 16);
        if (lj == 0) {
            float denom = mm + __logf(se);
            float numer = sp[0] + sp[1] + sp[2] + sp[3] + sp[4];
            int   sm    = si[0] + si[1] + si[2] + si[3] + si[4];
            int   last  = label[b * Tn + sm - 1];
            partial[b]  = denom - (numer + endT[last]);   // = -llh[b]
        }
    }

    // ---- last consumer block reduces partials -> out ----
    if (tid < 64) {
        int old = 0;
        if (tid == 0) {
            __threadfence();
            old = atomicAdd(cnt2, 1);
        }
        old = __shfl(old, 0);
        if (old == Bn - 1) {
            __threadfence();                 // acquire: other blocks' partial[] visible
            float pv = partial[tid];
#pragma unroll
            for (int off = 32; off > 0; off >>= 1) pv += __shfl_xor(pv, off);
            if (tid == 0) out[0] = pv * (1.0f / Bn);
        }
    }
}

extern "C" void kernel_launch(void* const* d_in, const int* in_sizes, int n_in,
                              void* d_out, int out_size, void* d_ws, size_t ws_size,
                              hipStream_t stream)
{
    // inputs: 0=length(unused) 1=word2vec 2=mask 3=label 4=W 5=b 6=start 7=end 8=trans
    const float* wv    = (const float*)d_in[1];
    const int*   mask  = (const int*)d_in[2];
    const int*   label = (const int*)d_in[3];
    const float* Wm    = (const float*)d_in[4];
    const float* bias  = (const float*)d_in[5];
    const float* st    = (const float*)d_in[6];
    const float* en    = (const float*)d_in[7];
    const float* tr    = (const float*)d_in[8];

    float* ws      = (float*)d_ws;
    float* eexp    = ws;                 // B*T*EMS = 393216 floats
    float* partial = ws + 393216;        // 64 floats
    int*   bcnt    = (int*)(ws + 393280); // 64 per-batch producer counters
    int*   cnt2    = bcnt + Bn;           // final-reduction counter
    float* out     = (float*)d_out;

    // Workspace is poisoned between iterations: counters must be re-zeroed.
    hipMemsetAsync(bcnt, 0, (Bn + 1) * sizeof(int), stream);

    hipLaunchKernelGGL(fused_kernel, dim3(512), dim3(320), 0, stream,
                       wv, Wm, bias, mask, label, tr, st, en,
                       eexp, partial, bcnt, cnt2, out);
}

// Round 2
// 40.070 us; speedup vs baseline: 3.8236x; 3.8236x over previous
//
#include <hip/hip_runtime.h>
#include <hip/hip_bf16.h>

// BERT_CRF, time-partitioned fusion. B=64, T=512, H=768, L=9.
//
// K1 emis_q_kernel: grid 256 = (b, quarter q). Each block:
//   - stages W as bf16 MFMA B-fragments in LDS (proven pattern),
//   - computes its 128 emission rows (8 tiles x 8 waves, 24 MFMA steps)
//     writing exp(em) ONLY to LDS (no global eexp roundtrip),
//   - numerator + mask partial sums over its 128 timesteps,
//   - 8 chunk products (16 steps each, proven scaled-product code, all
//     operands from LDS), pair-combined 8->4->2->1 to ONE 9x9 quarter
//     matrix (row-scaled) + per-row log-scales -> ~100 floats to global.
//   No cross-block dependencies, no fences. All 256 CUs stream wv.
//
// K2 comb_kernel: 64 blocks x 64 threads. Per batch: chain the 4 quarter
//   matrices with the proven shfl-based log-combine (depth 4), add
//   numerator, write partial[b]; last block (atomic cnt, proven election)
//   reduces -> out. cnt zeroed by K1 block 0 (workspace is poisoned).

#define Bn 64
#define Tn 512
#define Hn 768
#define Ln 9
#define EMS 12     // padded LDS emission row stride (floats)
#define CS 16      // time steps per chunk
#define NCHQ 8     // chunks per quarter
#define QT 128     // timesteps per block
#define KSTEPS 24  // 768 / 32

typedef short bf16x8 __attribute__((ext_vector_type(8)));   // 8 bf16 (4 VGPRs)
typedef float f32x4  __attribute__((ext_vector_type(4)));   // 4 fp32 acc

__device__ __forceinline__ short f2bf(float f) {
    return (short)__builtin_bit_cast(unsigned short, __float2bfloat16(f));
}

// ---------------- K1: per-(batch,quarter) emissions + chunk products ----------------
__global__ __launch_bounds__(512) void emis_q_kernel(
    const float* __restrict__ wv, const float* __restrict__ Wm,
    const float* __restrict__ bias, const int* __restrict__ mask,
    const int* __restrict__ label, const float* __restrict__ trans,
    const float* __restrict__ startT,
    float* __restrict__ Mq, float* __restrict__ lgq,
    float* __restrict__ numq, int* __restrict__ msq,
    float* __restrict__ em0, int* __restrict__ cnt)
{
    __shared__ bf16x8 wlds[KSTEPS * 64];     // 24576 B, W B-fragments
    __shared__ float  ldsE[QT][EMS];         // exp(emissions), 6144 B
    __shared__ int    ldsM[QT];              // mask slice
    __shared__ float  eTs[81];               // exp(transitions)
    __shared__ float  sM[NCHQ][Ln][Ln];      // chunk product matrices
    __shared__ float  sLg[NCHQ][Ln];         // chunk row log-scales
    __shared__ float  sp[8];
    __shared__ int    si[8];

    const int tid   = threadIdx.x;
    const int lane  = tid & 63;
    const int wid   = tid >> 6;
    const int bid   = blockIdx.x;
    const int b     = bid >> 2;
    const int q     = bid & 3;
    const int tbase = q * QT;

    if (bid == 0 && tid == 0) cnt[0] = 0;    // K2 runs strictly after K1
    if (tid < 81) eTs[tid] = __expf(trans[tid]);

    // Stage W (L=9 x H=768 fp32) as bf16 B-fragments in MFMA lane order:
    // entry (kk, lane): lane holds B[k = kk*32 + (lane>>4)*8 + j][n = lane&15],
    // B[k][n] = W[n][k]; n >= 9 -> zeros.
    for (int idx = tid; idx < KSTEPS * 64; idx += 512) {
        const int kk = idx >> 6, ln = idx & 63;
        const int n = ln & 15, kb2 = ln >> 4;
        bf16x8 v;
        if (n < Ln) {
            const float* src = Wm + n * Hn + kk * 32 + kb2 * 8;
#pragma unroll
            for (int j = 0; j < 8; ++j) v[j] = f2bf(src[j]);
        } else {
#pragma unroll
            for (int j = 0; j < 8; ++j) v[j] = 0;
        }
        wlds[idx] = v;
    }
    __syncthreads();

    // ---- emission phase: wave wid computes rows [bid*128 + wid*16, +16) ----
    {
        const int m  = lane & 15;            // A row within tile
        const int kb = lane >> 4;            // k-subblock (8 elems)
        const float* abase = wv + (size_t)(bid * QT + wid * 16 + m) * Hn + kb * 8;

        f32x4 acc = {0.f, 0.f, 0.f, 0.f};
#pragma unroll 4
        for (int kk = 0; kk < KSTEPS; ++kk) {
            float4 x0 = *reinterpret_cast<const float4*>(abase + kk * 32);
            float4 x1 = *reinterpret_cast<const float4*>(abase + kk * 32 + 4);
            bf16x8 a;
            a[0] = f2bf(x0.x); a[1] = f2bf(x0.y); a[2] = f2bf(x0.z); a[3] = f2bf(x0.w);
            a[4] = f2bf(x1.x); a[5] = f2bf(x1.y); a[6] = f2bf(x1.z); a[7] = f2bf(x1.w);
            bf16x8 bfr = wlds[kk * 64 + lane];
            acc = __builtin_amdgcn_mfma_f32_16x16x32_bf16(a, bfr, acc, 0, 0, 0);
        }
        // C/D layout: col = lane&15, row = (lane>>4)*4 + r. Write exp to LDS.
        const int l = lane & 15;
        if (l < Ln) {
            const float bl = bias[l];
#pragma unroll
            for (int r = 0; r < 4; ++r) {
                const int lrow = wid * 16 + (lane >> 4) * 4 + r;
                ldsE[lrow][l] = __expf(acc[r] + bl);
            }
        }
    }
    __syncthreads();

    // ---- numerator partials + mask staging (threads 0..127, one t each) ----
    float part = 0.f; int ms = 0;
    if (tid < QT) {
        const int gt  = tbase + tid;
        const int tag = label[b * Tn + gt];
        const int mk  = mask[b * Tn + gt];
        ldsM[tid] = mk; ms = mk;
        if (gt == 0) {
            part = startT[tag] + __logf(ldsE[0][tag]);
        } else if (mk) {
            const int prev = label[b * Tn + gt - 1];
            part = trans[prev * Ln + tag] + __logf(ldsE[tid][tag]);
        }
    }
#pragma unroll
    for (int off = 32; off > 0; off >>= 1) {
        part += __shfl_xor(part, off);
        ms   += __shfl_xor(ms, off);
    }
    if (lane == 0) { sp[wid] = part; si[wid] = ms; }
    __syncthreads();

    // ---- chunk products (threads 0..71), all operands from LDS ----
    if (tid < NCHQ * Ln) {
        float Tr[81];
#pragma unroll
        for (int i = 0; i < 81; ++i) Tr[i] = eTs[i];
        const int r = tid % Ln;
        const int c = tid / Ln;

        float v[9];
#pragma unroll
        for (int k = 0; k < 9; ++k) v[k] = (k == r) ? 1.f : 0.f;
        float lg = 0.f;

        int t0 = tbase + c * CS; if (t0 == 0) t0 = 1;   // only (q==0,c==0)
        const int t1 = tbase + (c + 1) * CS;

        int lt = t0 - tbase;
        float4 e0v = *reinterpret_cast<const float4*>(&ldsE[lt][0]);
        float4 e1v = *reinterpret_cast<const float4*>(&ldsE[lt][4]);
        float  e8  = ldsE[lt][8];
        int    mk  = ldsM[lt];

        for (int t = t0; t < t1; ++t) {
            float4 p0 = make_float4(0.f, 0.f, 0.f, 0.f), p1 = p0;
            float  p8 = 0.f; int pm = 0;
            if (t + 1 < t1) {
                const int nlt = t + 1 - tbase;
                p0 = *reinterpret_cast<const float4*>(&ldsE[nlt][0]);
                p1 = *reinterpret_cast<const float4*>(&ldsE[nlt][4]);
                p8 = ldsE[nlt][8];
                pm = ldsM[nlt];
            }
            if (mk) {
                float e[9] = {e0v.x, e0v.y, e0v.z, e0v.w, e1v.x, e1v.y, e1v.z, e1v.w, e8};
                float nv[9];
#pragma unroll
                for (int jj = 0; jj < 9; ++jj) {
                    float acc = v[0] * Tr[jj];
#pragma unroll
                    for (int k = 1; k < 9; ++k) acc += v[k] * Tr[k * 9 + jj];
                    nv[jj] = acc * e[jj];
                }
                float mx = nv[0];
#pragma unroll
                for (int jj = 1; jj < 9; ++jj) mx = fmaxf(mx, nv[jj]);
                float inv = 1.f / mx;
#pragma unroll
                for (int jj = 0; jj < 9; ++jj) v[jj] = nv[jj] * inv;
                lg += __logf(mx);
            }
            e0v = p0; e1v = p1; e8 = p8; mk = pm;
        }
#pragma unroll
        for (int jj = 0; jj < 9; ++jj) sM[c][r][jj] = v[jj];
        sLg[c][r] = lg;
    }
    // parallel small outputs (independent of chunk phase)
    if (q == 0 && tid >= 72 && tid < 81) em0[b * Ln + (tid - 72)] = ldsE[0][tid - 72];
    if (tid == 100) {
        float s = 0.f; int m2 = 0;
#pragma unroll
        for (int i = 0; i < 8; ++i) { s += sp[i]; m2 += si[i]; }
        numq[bid] = s; msq[bid] = m2;
    }
    __syncthreads();

    // ---- pair-combine 8 -> 4 -> 2 (in place, barrier-separated) ----
    for (int n = 4; n >= 2; n >>= 1) {
        float vout[9]; float lgout = 0.f;
        const bool act = tid < n * Ln;
        int p = 0, r = 0;
        if (act) {
            p = tid / Ln; r = tid % Ln;
            float mB = sLg[2 * p + 1][0];
#pragma unroll
            for (int k = 1; k < 9; ++k) mB = fmaxf(mB, sLg[2 * p + 1][k]);
            float tA[9];
#pragma unroll
            for (int k = 0; k < 9; ++k) tA[k] = sM[2 * p][r][k] * __expf(sLg[2 * p + 1][k] - mB);
#pragma unroll
            for (int jj = 0; jj < 9; ++jj) {
                float acc = tA[0] * sM[2 * p + 1][0][jj];
#pragma unroll
                for (int k = 1; k < 9; ++k) acc += tA[k] * sM[2 * p + 1][k][jj];
                vout[jj] = acc;
            }
            float mx = vout[0];
#pragma unroll
            for (int jj = 1; jj < 9; ++jj) mx = fmaxf(mx, vout[jj]);
            float inv = 1.f / mx;
#pragma unroll
            for (int jj = 0; jj < 9; ++jj) vout[jj] *= inv;
            lgout = sLg[2 * p][r] + mB + __logf(mx);
        }
        __syncthreads();
        if (act) {
#pragma unroll
            for (int jj = 0; jj < 9; ++jj) sM[p][r][jj] = vout[jj];
            sLg[p][r] = lgout;
        }
        __syncthreads();
    }

    // ---- final pair -> global quarter matrix ----
    if (tid < Ln) {
        const int r = tid;
        float mB = sLg[1][0];
#pragma unroll
        for (int k = 1; k < 9; ++k) mB = fmaxf(mB, sLg[1][k]);
        float tA[9];
#pragma unroll
        for (int k = 0; k < 9; ++k) tA[k] = sM[0][r][k] * __expf(sLg[1][k] - mB);
        float v[9];
#pragma unroll
        for (int jj = 0; jj < 9; ++jj) {
            float acc = tA[0] * sM[1][0][jj];
#pragma unroll
            for (int k = 1; k < 9; ++k) acc += tA[k] * sM[1][k][jj];
            v[jj] = acc;
        }
        float mx = v[0];
#pragma unroll
        for (int jj = 1; jj < 9; ++jj) mx = fmaxf(mx, v[jj]);
        float inv = 1.f / mx;
#pragma unroll
        for (int jj = 0; jj < 9; ++jj) Mq[bid * 81 + r * 9 + jj] = v[jj] * inv;
        lgq[bid * Ln + r] = sLg[0][r] + mB + __logf(mx);
    }
}

// ---------------- K2: combine 4 quarter matrices per batch ----------------
__global__ __launch_bounds__(64) void comb_kernel(
    const float* __restrict__ Mq, const float* __restrict__ lgq,
    const float* __restrict__ numq, const int* __restrict__ msq,
    const float* __restrict__ em0, const int* __restrict__ label,
    const float* __restrict__ startT, const float* __restrict__ endT,
    float* __restrict__ partial, int* __restrict__ cnt, float* __restrict__ out)
{
    __shared__ float cM[4][Ln][Ln];
    __shared__ float cLg[4][Ln];
    __shared__ float cem[Ln];
    __shared__ float cnum[4];
    __shared__ int   cms[4];

    const int b = blockIdx.x, tid = threadIdx.x;

    for (int i = tid; i < 4 * 81; i += 64) cM[i / 81][(i % 81) / 9][i % 9] = Mq[b * 324 + i];
    for (int i = tid; i < 4 * 9; i += 64)  cLg[i / 9][i % 9] = lgq[b * 36 + i];
    if (tid < Ln) cem[tid] = em0[b * Ln + tid];
    if (tid < 4) { cnum[tid] = numq[b * 4 + tid]; cms[tid] = msq[b * 4 + tid]; }
    __syncthreads();

    if (tid < 16) {
        const int lj = tid;
        const float NEG = -1e30f;
        float la = (lj < Ln) ? (startT[lj] + __logf(cem[lj])) : NEG;
        for (int c = 0; c < 4; ++c) {
            float mc[9];
#pragma unroll
            for (int rr = 0; rr < 9; ++rr) mc[rr] = (lj < Ln) ? cM[c][rr][lj] : 0.f;
            float x = (lj < Ln) ? (la + cLg[c][lj]) : NEG;
            float mm = x;
#pragma unroll
            for (int off = 1; off < 16; off <<= 1) mm = fmaxf(mm, __shfl_xor(mm, off, 16));
            float w = __expf(x - mm);                 // lj>=9 -> 0
            float sacc = 0.f;
#pragma unroll
            for (int rr = 0; rr < 9; ++rr) sacc += __shfl(w, rr, 16) * mc[rr];
            la = (lj < Ln) ? (mm + __logf(sacc)) : NEG;
        }
        float x = (lj < Ln) ? (la + endT[lj]) : NEG;
        float mm = x;
#pragma unroll
        for (int off = 1; off < 16; off <<= 1) mm = fmaxf(mm, __shfl_xor(mm, off, 16));
        float se = __expf(x - mm);
#pragma unroll
        for (int off = 1; off < 16; off <<= 1) se += __shfl_xor(se, off, 16);
        if (lj == 0) {
            float denom = mm + __logf(se);
            float numer = cnum[0] + cnum[1] + cnum[2] + cnum[3];
            int   sm    = cms[0] + cms[1] + cms[2] + cms[3];
            int   last  = label[b * Tn + sm - 1];
            partial[b]  = denom - (numer + endT[last]);   // = -llh[b]
        }
    }

    // last block reduces partials -> out (proven election pattern)
    int old = 0;
    if (tid == 0) {
        __threadfence();
        old = atomicAdd(cnt, 1);
    }
    old = __shfl(old, 0);
    if (old == Bn - 1) {
        __threadfence();                 // acquire: other blocks' partial[] visible
        float pv = partial[tid];
#pragma unroll
        for (int off = 32; off > 0; off >>= 1) pv += __shfl_xor(pv, off);
        if (tid == 0) out[0] = pv * (1.0f / Bn);
    }
}

extern "C" void kernel_launch(void* const* d_in, const int* in_sizes, int n_in,
                              void* d_out, int out_size, void* d_ws, size_t ws_size,
                              hipStream_t stream)
{
    // inputs: 0=length(unused) 1=word2vec 2=mask 3=label 4=W 5=b 6=start 7=end 8=trans
    const float* wv    = (const float*)d_in[1];
    const int*   mask  = (const int*)d_in[2];
    const int*   label = (const int*)d_in[3];
    const float* Wm    = (const float*)d_in[4];
    const float* bias  = (const float*)d_in[5];
    const float* st    = (const float*)d_in[6];
    const float* en    = (const float*)d_in[7];
    const float* tr    = (const float*)d_in[8];

    float* ws      = (float*)d_ws;
    float* Mq      = ws;                   // 256*81 = 20736
    float* lgq     = ws + 20736;           // 256*9  = 2304
    float* numq    = ws + 23040;           // 256
    int*   msq     = (int*)(ws + 23296);   // 256
    float* em0     = ws + 23552;           // 64*9 = 576
    float* partial = ws + 24128;           // 64
    int*   cnt     = (int*)(ws + 24192);   // 1
    float* out     = (float*)d_out;

    hipLaunchKernelGGL(emis_q_kernel, dim3(256), dim3(512), 0, stream,
                       wv, Wm, bias, mask, label, tr, st,
                       Mq, lgq, numq, msq, em0, cnt);
    hipLaunchKernelGGL(comb_kernel, dim3(Bn), dim3(64), 0, stream,
                       Mq, lgq, numq, msq, em0, label, st, en,
                       partial, cnt, out);
}